// Round 5
// baseline (171.078 us; speedup 1.0000x reference)
//
#include <hip/hip_runtime.h>

// B=4, S=4096, D=64, fp32. Softmax over QUERY axis (per key-column norm):
//   out[b,q,:] = sum_k exp(s[q,k]) * (1/sum_q' exp(s[q',k])) * V[k,:],  s = Q.K^T/8
// v5: ZERO-MOVEMENT P. Swapped QK^T leaves P[k][q] with lane(l15,g4) holding
// k = kt*16+g4*4+r, q=l15. The PV A-frag slot j needs k-slot g4*8+j -- so the VT
// image's k-columns are PERMUTED (col c holds k=((c>>2)&1)*16+((c>>3)<<2)+(c&3)),
// making the packed QK outputs *be* the PV A-fragment in-register. The apply
// inner loop has NO LDS ops: K reg-double-buffered, V loaded at iter top,
// register-dep-only ordering (fix for v3/v4's LDS-round-trip serialization and
// compiler load-sinking, which held MfmaUtil at 16%).

#define B_N 4
#define S_N 4096
#define D_N 64
#define BS_N (B_N * S_N)
#define NCHUNK 128            // 32-row chunks per batch
#define IMG_CH 8192           // bytes per chunk in every image
#define QSC (0.125f * 1.44269504088896f)

typedef __attribute__((ext_vector_type(4))) float f32x4;
typedef __attribute__((ext_vector_type(8))) short short8;
typedef __attribute__((ext_vector_type(4))) unsigned u32x4;
typedef unsigned long long u64;
typedef unsigned char uchar;

#define MFMA16(A, Bf, C) __builtin_amdgcn_mfma_f32_16x16x32_bf16((A), (Bf), (C), 0, 0, 0)

// Truncation hi/lo split: x == hi + lo + O(2^-16 x); residual exact in fp32.
__device__ __forceinline__ void split1(float x, unsigned short& h, unsigned short& l) {
  union { float f; unsigned u; } t; t.f = x;
  h = (unsigned short)(t.u >> 16);
  union { unsigned u; float f; } hv; hv.u = ((unsigned)h) << 16;
  union { float f; unsigned u; } r; r.f = x - hv.f;
  l = (unsigned short)(r.u >> 16);
}

__device__ __forceinline__ void splitFrag8(const f32x4 a, const f32x4 b, short8& hi, short8& lo) {
#pragma unroll
  for (int j = 0; j < 4; ++j) { unsigned short h, l; split1(a[j], h, l); hi[j] = (short)h; lo[j] = (short)l; }
#pragma unroll
  for (int j = 0; j < 4; ++j) { unsigned short h, l; split1(b[j], h, l); hi[4 + j] = (short)h; lo[4 + j] = (short)l; }
}

// ---------------------------------------------------------------------------
// prepKQ: fp32 [B*S][64] -> chunk images: row r (32/chunk) = [hi 128B][lo 128B].
// grid 1024: blocks 0..511 = K (scale 1), 512..1023 = Q (scale QSC).
// ---------------------------------------------------------------------------
__global__ __launch_bounds__(256) void sdpa_prepKQ(const float* __restrict__ K,
                                                   const float* __restrict__ Qm,
                                                   uchar* __restrict__ Kimg,
                                                   uchar* __restrict__ Qimg) {
  const int sel = blockIdx.x >> 9;
  const int c = blockIdx.x & 127;
  const int b = (blockIdx.x >> 7) & 3;
  const float* src = sel ? Qm : K;
  uchar* img = sel ? Qimg : Kimg;
  const float scale = sel ? QSC : 1.0f;
  const int t = threadIdx.x;
  const int r = t >> 3;
  const int d0 = (t & 7) * 8;
  const float* s = src + ((size_t)(b * S_N + c * 32 + r)) * D_N + d0;
  f32x4 x0 = *(const f32x4*)(s);
  f32x4 x1 = *(const f32x4*)(s + 4);
  x0 *= scale; x1 *= scale;
  short8 h8, l8;
  splitFrag8(x0, x1, h8, l8);
  uchar* dst = img + ((size_t)(b * NCHUNK + c)) * IMG_CH + r * 256 + d0 * 2;
  *(short8*)(dst) = h8;
  *(short8*)(dst + 128) = l8;
}

// ---------------------------------------------------------------------------
// stats4: lPart[qs][b][k] = sum over q-slice qs (512 q) of exp2(min(s,86)).
// grid 512, block 256; wave w = q-slice. K (64 k) register-resident; Q chunks
// double-buffered in regs. No barriers. (proven)
// ---------------------------------------------------------------------------
__global__ __launch_bounds__(256, 2) void sdpa_stats4(const uchar* __restrict__ Kimg,
                                                      const uchar* __restrict__ Qimg,
                                                      float* __restrict__ lPart) {
  const int tid = threadIdx.x, lane = tid & 63, w = tid >> 6;
  const int l15 = lane & 15, g4 = lane >> 4;
  const int xcd = blockIdx.x & 7;
  const int b = xcd >> 1;
  const int r = blockIdx.x >> 3;                  // [0,64)
  const int kt = ((r & 31) << 1) | (xcd & 1);     // [0,64) k-tile of 64
  const int qs = ((r >> 5) << 2) | w;             // [0,8) q-slice of 512

  short8 kh[4][2], kl[4][2];
#pragma unroll
  for (int kg = 0; kg < 4; ++kg) {
    const uchar* kb = Kimg + ((size_t)(b * NCHUNK + kt * 2 + (kg >> 1))) * IMG_CH
                    + ((kg & 1) * 16 + l15) * 256 + (g4 << 4);
    kh[kg][0] = *(const short8*)(kb);
    kh[kg][1] = *(const short8*)(kb + 64);
    kl[kg][0] = *(const short8*)(kb + 128);
    kl[kg][1] = *(const short8*)(kb + 192);
  }

  float lacc[4][4];
#pragma unroll
  for (int kg = 0; kg < 4; ++kg)
#pragma unroll
    for (int rr = 0; rr < 4; ++rr) lacc[kg][rr] = 0.f;

  const uchar* Qbase = Qimg + ((size_t)(b * NCHUNK + qs * 16)) * IMG_CH + l15 * 256 + (g4 << 4);

  short8 qb[2][2][4];
#pragma unroll
  for (int qt = 0; qt < 2; ++qt)
#pragma unroll
    for (int p = 0; p < 4; ++p)
      qb[0][qt][p] = *(const short8*)(Qbase + qt * 4096 + p * 64);

#pragma unroll 2
  for (int it = 0; it < 16; ++it) {
    const int cur = it & 1, nxt = cur ^ 1;
    if (it < 15) {
      const uchar* Qn = Qbase + (size_t)(it + 1) * IMG_CH;
#pragma unroll
      for (int qt = 0; qt < 2; ++qt)
#pragma unroll
        for (int p = 0; p < 4; ++p)
          qb[nxt][qt][p] = *(const short8*)(Qn + qt * 4096 + p * 64);
    }
#pragma unroll
    for (int qt = 0; qt < 2; ++qt) {
      short8 bh0 = qb[cur][qt][0], bh1 = qb[cur][qt][1];
      short8 bl0 = qb[cur][qt][2], bl1 = qb[cur][qt][3];
#pragma unroll
      for (int kg = 0; kg < 4; ++kg) {
        f32x4 acc = {0.f, 0.f, 0.f, 0.f};
        acc = MFMA16(kl[kg][0], bh0, acc);
        acc = MFMA16(kh[kg][0], bl0, acc);
        acc = MFMA16(kh[kg][0], bh0, acc);
        acc = MFMA16(kl[kg][1], bh1, acc);
        acc = MFMA16(kh[kg][1], bl1, acc);
        acc = MFMA16(kh[kg][1], bh1, acc);
#pragma unroll
        for (int rr = 0; rr < 4; ++rr)
          lacc[kg][rr] += exp2f(fminf(acc[rr], 86.f));
      }
    }
  }

#pragma unroll
  for (int off = 1; off < 16; off <<= 1)
#pragma unroll
    for (int kg = 0; kg < 4; ++kg)
#pragma unroll
      for (int rr = 0; rr < 4; ++rr)
        lacc[kg][rr] += __shfl_xor(lacc[kg][rr], off);

  if (l15 == 0) {
#pragma unroll
    for (int kg = 0; kg < 4; ++kg)
#pragma unroll
      for (int rr = 0; rr < 4; ++rr)
        lPart[(size_t)qs * BS_N + b * S_N + kt * 64 + kg * 16 + (g4 << 2) + rr] = lacc[kg][rr];
  }
}

__global__ void sdpa_finalize8(const float* __restrict__ lPart, float* __restrict__ rcpl) {
  int i = blockIdx.x * 256 + threadIdx.x;
  if (i < BS_N) {
    float s = 0.f;
#pragma unroll
    for (int j = 0; j < 8; ++j) s += lPart[(size_t)j * BS_N + i];
    rcpl[i] = 1.0f / s;
  }
}

// ---------------------------------------------------------------------------
// prepV5: VT chunk images with PERMUTED k-columns: row d (64/chunk) =
// [hi 64B][lo 64B]; column slot c holds V[k=perm(c)][d]*rcpl[k], where
// perm(c) = ((c>>2)&1)*16 + ((c>>3)<<2) + (c&3). This makes the QK output
// registers directly usable as the PV A-fragment.
// ---------------------------------------------------------------------------
__global__ __launch_bounds__(256) void sdpa_prepV5(const float* __restrict__ V,
                                                   const float* __restrict__ rcpl,
                                                   uchar* __restrict__ VT) {
  __shared__ float Vs[32][65];
  __shared__ float rls[32];
  const int c = blockIdx.x & 127;
  const int b = blockIdx.x >> 7;
  const int t = threadIdx.x;
  {
    const int k = t >> 3;
    const int d0 = (t & 7) * 8;
    const float* src = V + ((size_t)(b * S_N + c * 32 + k)) * D_N + d0;
    f32x4 x0 = *(const f32x4*)(src);
    f32x4 x1 = *(const f32x4*)(src + 4);
#pragma unroll
    for (int j = 0; j < 4; ++j) { Vs[k][d0 + j] = x0[j]; Vs[k][d0 + 4 + j] = x1[j]; }
    if (t < 32) rls[t] = rcpl[b * S_N + c * 32 + t];
  }
  __syncthreads();
  const int d = t >> 2;
  const int kg = t & 3;
  short8 h8, l8;
#pragma unroll
  for (int j = 0; j < 8; ++j) {
    const int cc = kg * 8 + j;
    const int k = (((cc >> 2) & 1) << 4) + (((cc >> 3)) << 2) + (cc & 3);
    float v = Vs[k][d] * rls[k];
    unsigned short h, l; split1(v, h, l);
    h8[j] = (short)h; l8[j] = (short)l;
  }
  uchar* dst = VT + ((size_t)(b * NCHUNK + c)) * IMG_CH + d * 128 + kg * 16;
  *(short8*)(dst) = h8;
  *(short8*)(dst + 64) = l8;
}

// ---------------------------------------------------------------------------
// apply5: grid 512 = b(4, XCD-paired) x qt(128 tiles of 32 q); block 256.
// Wave w = k-quarter (1024 k, 32 chunk-iters). Inner loop: NO LDS ops.
//   iter i: load V(i) | prefetch K(i+1) regs | QK(i) -> exp -> pack A-frags
//           in-register | PV(i). One barrier pair (final merge).
// ---------------------------------------------------------------------------
__global__ __launch_bounds__(256, 2) void sdpa_apply5(const float* __restrict__ Q,
                                                      const uchar* __restrict__ Kimg,
                                                      const uchar* __restrict__ VTimg,
                                                      float* __restrict__ Out) {
  __shared__ __attribute__((aligned(16))) float Comb[4][32 * 68];  // merge only

  const int tid = threadIdx.x, lane = tid & 63, w = tid >> 6;
  const int l15 = lane & 15, g4 = lane >> 4;
  const int xcd = blockIdx.x & 7;
  const int b = xcd >> 1;
  const int qt = ((blockIdx.x >> 3) << 1) | (xcd & 1);  // [0,128)

  // Q B-frags: raw fp32, scaled by QSC, hi/lo split (once per wave)
  short8 qh[2][2], ql[2][2];
#pragma unroll
  for (int qg = 0; qg < 2; ++qg) {
    const int qRow = qt * 32 + qg * 16 + l15;
    const float* Qp = Q + ((size_t)(b * S_N + qRow)) * D_N;
    f32x4 x0 = *(const f32x4*)(Qp + g4 * 8);
    f32x4 x1 = *(const f32x4*)(Qp + g4 * 8 + 4);
    f32x4 y0 = *(const f32x4*)(Qp + 32 + g4 * 8);
    f32x4 y1 = *(const f32x4*)(Qp + 36 + g4 * 8);
    x0 *= QSC; x1 *= QSC; y0 *= QSC; y1 *= QSC;
    splitFrag8(x0, x1, qh[qg][0], ql[qg][0]);
    splitFrag8(y0, y1, qh[qg][1], ql[qg][1]);
  }

  f32x4 accO[2][4];
#pragma unroll
  for (int qg = 0; qg < 2; ++qg)
#pragma unroll
    for (int dt = 0; dt < 4; ++dt) accO[qg][dt] = (f32x4){0.f, 0.f, 0.f, 0.f};

  const uchar* Kc = Kimg + ((size_t)(b * NCHUNK + w * 32)) * IMG_CH + l15 * 256 + (g4 << 4);
  const uchar* Vc = VTimg + ((size_t)(b * NCHUNK + w * 32)) * IMG_CH + l15 * 128 + (g4 << 4);

  // prologue: K chunk 0 resident
  short8 kb[2][2][4];  // [buf][kt][ah0,ah1,al0,al1]
#pragma unroll
  for (int kt = 0; kt < 2; ++kt)
#pragma unroll
    for (int p = 0; p < 4; ++p)
      kb[0][kt][p] = *(const short8*)(Kc + kt * 4096 + p * 64);

#pragma unroll 2
  for (int it = 0; it < 32; ++it) {
    const int cur = it & 1;
    const int nxt = cur ^ 1;

    // V(it): issued at top, consumed after QK+exp (~400 cy later)
    short8 vv[4][2];
    {
      const uchar* Vn = Vc + (size_t)it * IMG_CH;
#pragma unroll
      for (int dt = 0; dt < 4; ++dt) {
        vv[dt][0] = *(const short8*)(Vn + dt * 2048);
        vv[dt][1] = *(const short8*)(Vn + dt * 2048 + 64);
      }
    }

    // prefetch K(it+1)
    if (it < 31) {
      const uchar* Kn = Kc + (size_t)(it + 1) * IMG_CH;
#pragma unroll
      for (int kt = 0; kt < 2; ++kt)
#pragma unroll
        for (int p = 0; p < 4; ++p)
          kb[nxt][kt][p] = *(const short8*)(Kn + kt * 4096 + p * 64);
    }

    // QK(it), swapped (A=K, B=Q): D[k][q]; lane holds k = kt*16+g4*4+r, q=l15.
    // Pack exp results directly into PV A-frags: slot dword kt*2+pair.
    u32x4 paH[2], paL[2];
#pragma unroll
    for (int kt = 0; kt < 2; ++kt) {
      short8 ah0 = kb[cur][kt][0], ah1 = kb[cur][kt][1];
      short8 al0 = kb[cur][kt][2], al1 = kb[cur][kt][3];
#pragma unroll
      for (int qg = 0; qg < 2; ++qg) {
        f32x4 acc = {0.f, 0.f, 0.f, 0.f};
        acc = MFMA16(al0, qh[qg][0], acc);
        acc = MFMA16(ah0, ql[qg][0], acc);
        acc = MFMA16(ah0, qh[qg][0], acc);
        acc = MFMA16(al1, qh[qg][1], acc);
        acc = MFMA16(ah1, ql[qg][1], acc);
        acc = MFMA16(ah1, qh[qg][1], acc);
#pragma unroll
        for (int pair = 0; pair < 2; ++pair) {
          float p0 = exp2f(fminf(acc[2 * pair + 0], 86.f));
          float p1 = exp2f(fminf(acc[2 * pair + 1], 86.f));
          unsigned short h0, l0, h1, l1;
          split1(p0, h0, l0);
          split1(p1, h1, l1);
          paH[qg][kt * 2 + pair] = (unsigned)h0 | ((unsigned)h1 << 16);
          paL[qg][kt * 2 + pair] = (unsigned)l0 | ((unsigned)l1 << 16);
        }
      }
    }

    // PV(it): A = in-register P frags, B = permuted-VT frags
    short8 pah[2], pal[2];
#pragma unroll
    for (int qg = 0; qg < 2; ++qg) {
      pah[qg] = __builtin_bit_cast(short8, paH[qg]);
      pal[qg] = __builtin_bit_cast(short8, paL[qg]);
    }
#pragma unroll
    for (int dt = 0; dt < 4; ++dt)
#pragma unroll
      for (int qg = 0; qg < 2; ++qg) {
        accO[qg][dt] = MFMA16(pal[qg], vv[dt][0], accO[qg][dt]);
        accO[qg][dt] = MFMA16(pah[qg], vv[dt][1], accO[qg][dt]);
        accO[qg][dt] = MFMA16(pah[qg], vv[dt][0], accO[qg][dt]);
      }
  }

  // merge the 4 k-quarter partials (only barriers in the kernel)
  __syncthreads();
  float* CombW = Comb[w];
#pragma unroll
  for (int qg = 0; qg < 2; ++qg)
#pragma unroll
    for (int dt = 0; dt < 4; ++dt)
#pragma unroll
      for (int r = 0; r < 4; ++r)
        CombW[(qg * 16 + (g4 << 2) + r) * 68 + dt * 16 + l15] = accO[qg][dt][r];
  __syncthreads();
  {
    const int row = tid >> 3;   // 0..31
    const int cb = tid & 7;     // 0..7
    f32x4 s0 = {0.f, 0.f, 0.f, 0.f}, s1 = {0.f, 0.f, 0.f, 0.f};
#pragma unroll
    for (int w2 = 0; w2 < 4; ++w2) {
      const float* p = Comb[w2] + row * 68 + cb * 8;
      s0 += *(const f32x4*)(p);
      s1 += *(const f32x4*)(p + 4);
    }
    float* Op = Out + ((size_t)(b * S_N + qt * 32 + row)) * D_N + cb * 8;
    *(f32x4*)(Op) = s0;
    *(f32x4*)(Op + 4) = s1;
  }
}

extern "C" void kernel_launch(void* const* d_in, const int* in_sizes, int n_in,
                              void* d_out, int out_size, void* d_ws, size_t ws_size,
                              hipStream_t stream) {
  (void)in_sizes; (void)n_in; (void)out_size;
  const float* Q = (const float*)d_in[0];
  const float* K = (const float*)d_in[1];
  const float* V = (const float*)d_in[2];
  float* out = (float*)d_out;
  uchar* ws = (uchar*)d_ws;

  const size_t imgSz = (size_t)B_N * NCHUNK * IMG_CH;          // 4 MB
  const size_t offK = 0;
  const size_t offQV = imgSz;                                  // Q image; VT aliases after stats
  const size_t offLP = 2 * imgSz;
  const size_t offRC = offLP + (size_t)8 * BS_N * 4;
  const size_t need = offRC + (size_t)BS_N * 4;                // ~8.9 MB (proven available)

  if (ws_size < need) return;
  float* lPart = (float*)(ws + offLP);
  float* rcpl = (float*)(ws + offRC);

  sdpa_prepKQ<<<dim3(1024), dim3(256), 0, stream>>>(K, Q, ws + offK, ws + offQV);
  sdpa_stats4<<<dim3(512), dim3(256), 0, stream>>>(ws + offK, ws + offQV, lPart);
  sdpa_finalize8<<<dim3(BS_N / 256), dim3(256), 0, stream>>>(lPart, rcpl);
  sdpa_prepV5<<<dim3(512), dim3(256), 0, stream>>>(V, rcpl, ws + offQV);
  sdpa_apply5<<<dim3(512), dim3(256), 0, stream>>>(Q, ws + offK, ws + offQV, out);
}

// Round 6
// 122.898 us; speedup vs baseline: 1.3920x; 1.3920x over previous
//
#include <hip/hip_runtime.h>

// B=4, S=4096, D=64, fp32. Softmax over QUERY axis (per key-column norm):
//   out[b,q,:] = sum_k exp(s[q,k]) * (1/sum_q' exp(s[q',k])) * V[k,:],  s = Q.K^T/8
// v6: TLP + perfect coalescing (v3/v4/v5 all ~129us: compiler sinks prefetches,
// 2 waves/SIMD can't hide L2 latency -> raise occupancy instead of fighting ILP).
//   - images stored FRAGMENT-ORDERED: every MFMA-fragment load is
//     base + seg*1024 + lane*16 (64-lane contiguous 1KB).
//   - apply6: 512-thread blocks (2 qsub x 4 k-quarter waves), grid 512
//     -> 16 waves/CU (4/SIMD). Inner loop: zero LDS, permuted-VT in-register P.
//   - stats6: 32-k tiles, grid 1024 -> 16 waves/CU.
// Numerics identical to v5 (hi/lo split, 3-MFMA products) -> bit-identical out.

#define B_N 4
#define S_N 4096
#define D_N 64
#define BS_N (B_N * S_N)
#define NCHUNK 128            // 32-row chunks per batch
#define IMG_CH 8192           // bytes per chunk in every image
#define QSC (0.125f * 1.44269504088896f)

typedef __attribute__((ext_vector_type(4))) float f32x4;
typedef __attribute__((ext_vector_type(8))) short short8;
typedef __attribute__((ext_vector_type(4))) unsigned u32x4;
typedef unsigned long long u64;
typedef unsigned char uchar;

#define MFMA16(A, Bf, C) __builtin_amdgcn_mfma_f32_16x16x32_bf16((A), (Bf), (C), 0, 0, 0)

// Truncation hi/lo split: x == hi + lo + O(2^-16 x); residual exact in fp32.
__device__ __forceinline__ void split1(float x, unsigned short& h, unsigned short& l) {
  union { float f; unsigned u; } t; t.f = x;
  h = (unsigned short)(t.u >> 16);
  union { unsigned u; float f; } hv; hv.u = ((unsigned)h) << 16;
  union { float f; unsigned u; } r; r.f = x - hv.f;
  l = (unsigned short)(r.u >> 16);
}

__device__ __forceinline__ void splitFrag8(const f32x4 a, const f32x4 b, short8& hi, short8& lo) {
#pragma unroll
  for (int j = 0; j < 4; ++j) { unsigned short h, l; split1(a[j], h, l); hi[j] = (short)h; lo[j] = (short)l; }
#pragma unroll
  for (int j = 0; j < 4; ++j) { unsigned short h, l; split1(b[j], h, l); hi[4 + j] = (short)h; lo[4 + j] = (short)l; }
}

// ---------------------------------------------------------------------------
// prepKQ: fp32 [B*S][64] -> FRAGMENT-ORDERED chunk images.
// Chunk (8KB) = 2 half-chunks (kt) x 4 segs (p: hi-d0..31, hi-d32..63, lo-d0..31,
// lo-d32..63) x 1KB; byte addr = kt*4096 + p*1024 + lane*16, lane = g4*16+l15,
// content = rows kt*16+l15, d = p-part + g4*8 .. +7.
// grid 1024: blocks 0..511 = K (scale 1), 512..1023 = Q (scale QSC).
// ---------------------------------------------------------------------------
__global__ __launch_bounds__(256) void sdpa_prepKQ(const float* __restrict__ K,
                                                   const float* __restrict__ Qm,
                                                   uchar* __restrict__ Kimg,
                                                   uchar* __restrict__ Qimg) {
  const int sel = blockIdx.x >> 9;
  const int c = blockIdx.x & 127;
  const int b = (blockIdx.x >> 7) & 3;
  const float* src = sel ? Qm : K;
  uchar* img = sel ? Qimg : Kimg;
  const float scale = sel ? QSC : 1.0f;
  const int t = threadIdx.x;
  const int r = t >> 3;          // 0..31 row in chunk
  const int d0 = (t & 7) * 8;    // 0..56
  const float* s = src + ((size_t)(b * S_N + c * 32 + r)) * D_N + d0;
  f32x4 x0 = *(const f32x4*)(s);
  f32x4 x1 = *(const f32x4*)(s + 4);
  x0 *= scale; x1 *= scale;
  short8 h8, l8;
  splitFrag8(x0, x1, h8, l8);
  const int kt = r >> 4;
  const int lane = ((d0 & 31) >> 3) * 16 + (r & 15);
  const int ph = d0 >> 5;  // 0/1
  uchar* base = img + ((size_t)(b * NCHUNK + c)) * IMG_CH + kt * 4096 + lane * 16;
  *(short8*)(base + ph * 1024) = h8;
  *(short8*)(base + (2 + ph) * 1024) = l8;
}

// ---------------------------------------------------------------------------
// stats6: lPart[qs][b][k] = sum over q-slice qs (512 q) of exp2(min(s,86)).
// grid 1024 (4 blocks/CU -> 16 waves/CU), block 256; wave w -> q-slice.
// 32 k register-resident per wave; Q chunks double-buffered in regs.
// ---------------------------------------------------------------------------
__global__ __launch_bounds__(256, 4) void sdpa_stats6(const uchar* __restrict__ Kimg,
                                                      const uchar* __restrict__ Qimg,
                                                      float* __restrict__ lPart) {
  const int tid = threadIdx.x, lane = tid & 63, w = tid >> 6;
  const int l15 = lane & 15, g4 = lane >> 4;
  const int xcd = blockIdx.x & 7;
  const int b = xcd >> 1;
  const int r = blockIdx.x >> 3;                  // [0,128)
  const int kt = ((r & 63) << 1) | (xcd & 1);     // [0,128) 32-k tile
  const int qs = ((r >> 6) << 2) | w;             // [0,8) q-slice of 512

  // K resident: one chunk, kg 0..1 (rows kg*16+l15)
  const uchar* kc = Kimg + ((size_t)(b * NCHUNK + kt)) * IMG_CH + lane * 16;
  short8 kh[2][2], kl[2][2];
#pragma unroll
  for (int kg = 0; kg < 2; ++kg) {
    kh[kg][0] = *(const short8*)(kc + (kg * 4 + 0) * 1024);
    kh[kg][1] = *(const short8*)(kc + (kg * 4 + 1) * 1024);
    kl[kg][0] = *(const short8*)(kc + (kg * 4 + 2) * 1024);
    kl[kg][1] = *(const short8*)(kc + (kg * 4 + 3) * 1024);
  }

  float lacc[2][4];
#pragma unroll
  for (int kg = 0; kg < 2; ++kg)
#pragma unroll
    for (int rr = 0; rr < 4; ++rr) lacc[kg][rr] = 0.f;

  const uchar* Qbase = Qimg + ((size_t)(b * NCHUNK + qs * 16)) * IMG_CH + lane * 16;

  short8 qb[2][2][4];
#pragma unroll
  for (int qt = 0; qt < 2; ++qt)
#pragma unroll
    for (int p = 0; p < 4; ++p)
      qb[0][qt][p] = *(const short8*)(Qbase + (qt * 4 + p) * 1024);

#pragma unroll 2
  for (int it = 0; it < 16; ++it) {
    const int cur = it & 1, nxt = cur ^ 1;
    if (it < 15) {
      const uchar* Qn = Qbase + (size_t)(it + 1) * IMG_CH;
#pragma unroll
      for (int qt = 0; qt < 2; ++qt)
#pragma unroll
        for (int p = 0; p < 4; ++p)
          qb[nxt][qt][p] = *(const short8*)(Qn + (qt * 4 + p) * 1024);
    }
#pragma unroll
    for (int qt = 0; qt < 2; ++qt) {
      short8 bh0 = qb[cur][qt][0], bh1 = qb[cur][qt][1];
      short8 bl0 = qb[cur][qt][2], bl1 = qb[cur][qt][3];
#pragma unroll
      for (int kg = 0; kg < 2; ++kg) {
        f32x4 acc = {0.f, 0.f, 0.f, 0.f};
        acc = MFMA16(kl[kg][0], bh0, acc);
        acc = MFMA16(kh[kg][0], bl0, acc);
        acc = MFMA16(kh[kg][0], bh0, acc);
        acc = MFMA16(kl[kg][1], bh1, acc);
        acc = MFMA16(kh[kg][1], bl1, acc);
        acc = MFMA16(kh[kg][1], bh1, acc);
#pragma unroll
        for (int rr = 0; rr < 4; ++rr)
          lacc[kg][rr] += exp2f(fminf(acc[rr], 86.f));
      }
    }
  }

#pragma unroll
  for (int off = 1; off < 16; off <<= 1)
#pragma unroll
    for (int kg = 0; kg < 2; ++kg)
#pragma unroll
      for (int rr = 0; rr < 4; ++rr)
        lacc[kg][rr] += __shfl_xor(lacc[kg][rr], off);

  if (l15 == 0) {
#pragma unroll
    for (int kg = 0; kg < 2; ++kg)
#pragma unroll
      for (int rr = 0; rr < 4; ++rr)
        lPart[(size_t)qs * BS_N + b * S_N + kt * 32 + kg * 16 + (g4 << 2) + rr] = lacc[kg][rr];
  }
}

__global__ void sdpa_finalize8(const float* __restrict__ lPart, float* __restrict__ rcpl) {
  int i = blockIdx.x * 256 + threadIdx.x;
  if (i < BS_N) {
    float s = 0.f;
#pragma unroll
    for (int j = 0; j < 8; ++j) s += lPart[(size_t)j * BS_N + i];
    rcpl[i] = 1.0f / s;
  }
}

// ---------------------------------------------------------------------------
// prepV6: fragment-ordered VT chunk images with PERMUTED k-columns.
// Chunk = 4 dt x [hi 1KB | lo 1KB]; addr = dt*2048 + half*1024 + lane*16;
// content: d = dt*16 + (lane&15), col slots cc = (lane>>4)*8..+7,
// value = split(V[k=perm(cc)][d] * rcpl[k]), perm(c)=((c>>2)&1)*16+((c>>3)<<2)+(c&3).
// ---------------------------------------------------------------------------
__global__ __launch_bounds__(256) void sdpa_prepV6(const float* __restrict__ V,
                                                   const float* __restrict__ rcpl,
                                                   uchar* __restrict__ VT) {
  __shared__ float Vs[32][65];
  __shared__ float rls[32];
  const int c = blockIdx.x & 127;
  const int b = blockIdx.x >> 7;
  const int t = threadIdx.x;
  {
    const int k = t >> 3;
    const int d0 = (t & 7) * 8;
    const float* src = V + ((size_t)(b * S_N + c * 32 + k)) * D_N + d0;
    f32x4 x0 = *(const f32x4*)(src);
    f32x4 x1 = *(const f32x4*)(src + 4);
#pragma unroll
    for (int j = 0; j < 4; ++j) { Vs[k][d0 + j] = x0[j]; Vs[k][d0 + 4 + j] = x1[j]; }
    if (t < 32) rls[t] = rcpl[b * S_N + c * 32 + t];
  }
  __syncthreads();
  const int d = t >> 2;
  const int kg = t & 3;
  short8 h8, l8;
#pragma unroll
  for (int j = 0; j < 8; ++j) {
    const int cc = kg * 8 + j;
    const int k = (((cc >> 2) & 1) << 4) + (((cc >> 3)) << 2) + (cc & 3);
    float v = Vs[k][d] * rls[k];
    unsigned short h, l; split1(v, h, l);
    h8[j] = (short)h; l8[j] = (short)l;
  }
  const int lane = kg * 16 + (d & 15);
  uchar* base = VT + ((size_t)(b * NCHUNK + c)) * IMG_CH + (d >> 4) * 2048 + lane * 16;
  *(short8*)(base) = h8;
  *(short8*)(base + 1024) = l8;
}

// ---------------------------------------------------------------------------
// apply6: grid 512 = b(4, XCD-paired) x qt(128 tiles of 32 q); block 512 =
// 8 waves (qsub = w>>2 picks 16 q; kq = w&3 picks k-quarter, 32 chunk-iters).
// 2 blocks/CU x 8 waves = 16 waves/CU. Inner loop: NO LDS ops, all loads
// 64-lane contiguous. Merge 4 k-partials per qsub via LDS at end.
// ---------------------------------------------------------------------------
__global__ __launch_bounds__(512, 4) void sdpa_apply6(const float* __restrict__ Q,
                                                      const uchar* __restrict__ Kimg,
                                                      const uchar* __restrict__ VTimg,
                                                      float* __restrict__ Out) {
  __shared__ __attribute__((aligned(16))) float Comb[8][16 * 68];  // 34816 B

  const int tid = threadIdx.x, lane = tid & 63, w = tid >> 6;
  const int l15 = lane & 15, g4 = lane >> 4;
  const int qsub = w >> 2, kq = w & 3;
  const int xcd = blockIdx.x & 7;
  const int b = xcd >> 1;
  const int qt = ((blockIdx.x >> 3) << 1) | (xcd & 1);  // [0,128)

  // Q B-frags: this wave's 16 q rows, scaled + hi/lo split
  short8 qh[2], ql[2];
  {
    const int qRow = qt * 32 + qsub * 16 + l15;
    const float* Qp = Q + ((size_t)(b * S_N + qRow)) * D_N;
    f32x4 x0 = *(const f32x4*)(Qp + g4 * 8);
    f32x4 x1 = *(const f32x4*)(Qp + g4 * 8 + 4);
    f32x4 y0 = *(const f32x4*)(Qp + 32 + g4 * 8);
    f32x4 y1 = *(const f32x4*)(Qp + 36 + g4 * 8);
    x0 *= QSC; x1 *= QSC; y0 *= QSC; y1 *= QSC;
    splitFrag8(x0, x1, qh[0], ql[0]);
    splitFrag8(y0, y1, qh[1], ql[1]);
  }

  f32x4 accO[4];
#pragma unroll
  for (int dt = 0; dt < 4; ++dt) accO[dt] = (f32x4){0.f, 0.f, 0.f, 0.f};

  const uchar* Kc = Kimg + ((size_t)(b * NCHUNK + kq * 32)) * IMG_CH + lane * 16;
  const uchar* Vc = VTimg + ((size_t)(b * NCHUNK + kq * 32)) * IMG_CH + lane * 16;

  // prologue: K chunk 0 resident
  short8 kb[2][2][4];  // [buf][kt][ah0,ah1,al0,al1]
#pragma unroll
  for (int kt = 0; kt < 2; ++kt)
#pragma unroll
    for (int p = 0; p < 4; ++p)
      kb[0][kt][p] = *(const short8*)(Kc + (kt * 4 + p) * 1024);

#pragma unroll 2
  for (int it = 0; it < 32; ++it) {
    const int cur = it & 1;
    const int nxt = cur ^ 1;

    // V(it): issued at top, consumed after QK+exp
    short8 vv[4][2];
    {
      const uchar* Vn = Vc + (size_t)it * IMG_CH;
#pragma unroll
      for (int dt = 0; dt < 4; ++dt) {
        vv[dt][0] = *(const short8*)(Vn + dt * 2048);
        vv[dt][1] = *(const short8*)(Vn + dt * 2048 + 1024);
      }
    }

    // prefetch K(it+1)
    if (it < 31) {
      const uchar* Kn = Kc + (size_t)(it + 1) * IMG_CH;
#pragma unroll
      for (int kt = 0; kt < 2; ++kt)
#pragma unroll
        for (int p = 0; p < 4; ++p)
          kb[nxt][kt][p] = *(const short8*)(Kn + (kt * 4 + p) * 1024);
    }

    // QK(it), swapped (A=K, B=Q): D[k][q]; lane holds k = kt*16+g4*4+r, q=l15.
    // exp results pack directly into the PV A-fragment (permuted-VT trick).
    u32x4 paH, paL;
#pragma unroll
    for (int kt = 0; kt < 2; ++kt) {
      short8 ah0 = kb[cur][kt][0], ah1 = kb[cur][kt][1];
      short8 al0 = kb[cur][kt][2], al1 = kb[cur][kt][3];
      f32x4 acc = {0.f, 0.f, 0.f, 0.f};
      acc = MFMA16(al0, qh[0], acc);
      acc = MFMA16(ah0, ql[0], acc);
      acc = MFMA16(ah0, qh[0], acc);
      acc = MFMA16(al1, qh[1], acc);
      acc = MFMA16(ah1, ql[1], acc);
      acc = MFMA16(ah1, qh[1], acc);
#pragma unroll
      for (int pair = 0; pair < 2; ++pair) {
        float p0 = exp2f(fminf(acc[2 * pair + 0], 86.f));
        float p1 = exp2f(fminf(acc[2 * pair + 1], 86.f));
        unsigned short h0, l0, h1, l1;
        split1(p0, h0, l0);
        split1(p1, h1, l1);
        paH[kt * 2 + pair] = (unsigned)h0 | ((unsigned)h1 << 16);
        paL[kt * 2 + pair] = (unsigned)l0 | ((unsigned)l1 << 16);
      }
    }

    short8 pah = __builtin_bit_cast(short8, paH);
    short8 pal = __builtin_bit_cast(short8, paL);
#pragma unroll
    for (int dt = 0; dt < 4; ++dt) {
      accO[dt] = MFMA16(pal, vv[dt][0], accO[dt]);
      accO[dt] = MFMA16(pah, vv[dt][1], accO[dt]);
      accO[dt] = MFMA16(pah, vv[dt][0], accO[dt]);
    }
  }

  // merge the 4 k-quarter partials per qsub (only barriers in the kernel)
  __syncthreads();
  {
    float* CombW = Comb[w];
#pragma unroll
    for (int dt = 0; dt < 4; ++dt)
#pragma unroll
      for (int r = 0; r < 4; ++r)
        CombW[((g4 << 2) + r) * 68 + dt * 16 + l15] = accO[dt][r];
  }
  __syncthreads();
  {
    const int row = tid >> 4;   // 0..31
    const int cb = tid & 15;    // 0..15
    const int qs2 = row >> 4;
    const int rl = row & 15;
    f32x4 s = {0.f, 0.f, 0.f, 0.f};
#pragma unroll
    for (int kq2 = 0; kq2 < 4; ++kq2)
      s += *(const f32x4*)(&Comb[qs2 * 4 + kq2][rl * 68 + cb * 4]);
    *(f32x4*)(Out + ((size_t)(b * S_N + qt * 32 + row)) * D_N + cb * 4) = s;
  }
}

extern "C" void kernel_launch(void* const* d_in, const int* in_sizes, int n_in,
                              void* d_out, int out_size, void* d_ws, size_t ws_size,
                              hipStream_t stream) {
  (void)in_sizes; (void)n_in; (void)out_size;
  const float* Q = (const float*)d_in[0];
  const float* K = (const float*)d_in[1];
  const float* V = (const float*)d_in[2];
  float* out = (float*)d_out;
  uchar* ws = (uchar*)d_ws;

  const size_t imgSz = (size_t)B_N * NCHUNK * IMG_CH;          // 4 MB
  const size_t offK = 0;
  const size_t offQV = imgSz;                                  // Q image; VT aliases after stats
  const size_t offLP = 2 * imgSz;
  const size_t offRC = offLP + (size_t)8 * BS_N * 4;
  const size_t need = offRC + (size_t)BS_N * 4;                // ~8.56 MiB (proven available)

  if (ws_size < need) return;
  float* lPart = (float*)(ws + offLP);
  float* rcpl = (float*)(ws + offRC);

  sdpa_prepKQ<<<dim3(1024), dim3(256), 0, stream>>>(K, Q, ws + offK, ws + offQV);
  sdpa_stats6<<<dim3(1024), dim3(256), 0, stream>>>(ws + offK, ws + offQV, lPart);
  sdpa_finalize8<<<dim3(BS_N / 256), dim3(256), 0, stream>>>(lPart, rcpl);
  sdpa_prepV6<<<dim3(512), dim3(256), 0, stream>>>(V, rcpl, ws + offQV);
  sdpa_apply6<<<dim3(512), dim3(512), 0, stream>>>(Q, ws + offK, ws + offQV, out);
}